// Round 2
// baseline (311.918 us; speedup 1.0000x reference)
//
#include <hip/hip_runtime.h>

#define ZYX (64 * 128 * 128) /* 1048576 */
#define CAP 2048
#define MMAX 1024
#define NSLOT_MAX 16 /* MMAX/64 */
#define RSLOTS 4     /* register-resident slots: candidates 0..255 */
#define KEPT_MAX 512
#define CLS_THR 0.5f
#define IOU_THR 0.5f

// ---------------- decode helper (matches reference _decode exactly) ----------
__device__ __forceinline__ void decode_one(const float* __restrict__ pb, int f,
                                           float& cx, float& cy, float& cz,
                                           float& w, float& h, float& l, float& th) {
    const float TM[8] = {-0.25f, 0.01f, 0.26f, 0.46f, 0.26f, 0.62f, 0.69f, 1.46f};
    const float TS[8] = {0.93f, 0.26f, 0.53f, 0.89f, 1.11f, 0.13f, 0.16f, 0.19f};
    int z = f >> 14;
    int y = (f >> 7) & 127;
    int x = f & 127;
    float r[8];
#pragma unroll
    for (int c = 0; c < 8; ++c)
        r[c] = pb[(size_t)(c + 1) * ZYX + f] * TS[c] + TM[c];
    th = atan2f(r[1], r[0]);
    cx = (-16.0f + 0.25f * (float)x) + r[2];
    cy = (-16.0f + 0.25f * (float)y) + r[3];
    cz = (-16.0f + 0.5f * (float)z) + r[4];
    w = expf(r[5]);
    h = expf(r[6]);
    l = expf(r[7]);
}

__device__ __forceinline__ void corner_boxes(float cx, float cy, float cz,
                                             float w, float h, float l, float th,
                                             float& xmn, float& ymn, float& xmx, float& ymx,
                                             float& zmn, float& zmx) {
    float ct = cosf(th), st = sinf(th);
    xmn = 1e30f; xmx = -1e30f; ymn = 1e30f; ymx = -1e30f; zmn = 1e30f; zmx = -1e30f;
#pragma unroll
    for (int k = 0; k < 8; ++k) {
        float sx = (k & 4) ? -1.0f : 1.0f;
        float sy = (k & 2) ? -1.0f : 1.0f;
        float sz = (k & 1) ? -1.0f : 1.0f;
        float ox = 0.5f * sx * w;
        float oy = 0.5f * sy * h;
        float oz = 0.5f * sz * l;
        float px = cx + ct * ox + st * oz;
        float py = cy + oy;
        float pz = cz - st * ox + ct * oz;
        xmn = fminf(xmn, px); xmx = fmaxf(xmx, px);
        ymn = fminf(ymn, py); ymx = fmaxf(ymx, py);
        zmn = fminf(zmn, pz); zmx = fmaxf(zmx, pz);
    }
}

// ---------------- kernel 1: compact candidates with score > CLS_THR ----------
__global__ __launch_bounds__(256) void collect_kernel(const float* __restrict__ points, int B,
                                                      int* __restrict__ cnt,
                                                      float* __restrict__ csc,
                                                      int* __restrict__ cidx) {
    int g = blockIdx.x * blockDim.x + threadIdx.x;
    int per_b4 = ZYX / 4;
    int total4 = B * per_b4;
    if (g >= total4) return;
    int b = g / per_b4;
    int f4 = g - b * per_b4;
    const float4* p = (const float4*)(points + (size_t)b * 9 * ZYX);
    float4 v = p[f4];
    float vals[4] = {v.x, v.y, v.z, v.w};
    int f = f4 * 4;
#pragma unroll
    for (int k = 0; k < 4; ++k) {
        if (vals[k] > CLS_THR) {
            int pos = atomicAdd(&cnt[b], 1);
            if (pos < CAP) {
                csc[b * CAP + pos] = vals[k];
                cidx[b * CAP + pos] = f + k;
            }
        }
    }
}

// ---------------- kernel 2: rank, decode, ballot-NMS, emit -------------------
__global__ __launch_bounds__(256) void nms_kernel(const float* __restrict__ points,
                                                  const int* __restrict__ cnt,
                                                  const float* __restrict__ csc,
                                                  const int* __restrict__ cidx,
                                                  float* __restrict__ out,
                                                  int B, int n_out) {
    // union region: phase A = raw candidates (CAP*8 = 16 KB);
    // phase B = AoS boxes (MMAX*(16+16+8) = 40 KB)
    __shared__ __align__(16) char s_u[MMAX * 40];
    float* s_rawsc = (float*)s_u;                    // [CAP]
    int* s_rawidx = (int*)(s_u + CAP * 4);           // [CAP]
    float4* s_bxy = (float4*)s_u;                    // [MMAX] (x0,y0,x1,y1)
    float4* s_byz = (float4*)(s_u + MMAX * 16);      // [MMAX] (a0,b0,a1,b1)
    float2* s_ar = (float2*)(s_u + MMAX * 32);       // [MMAX] (area_xy, area_yz)
    __shared__ float s_sc[MMAX];
    __shared__ int s_idx[MMAX];
    __shared__ int s_kept[KEPT_MAX];
    __shared__ unsigned long long s_supx[NSLOT_MAX], s_supy[NSLOT_MAX];
    __shared__ int s_nkept;

    int b = blockIdx.x;
    int tid = threadIdx.x;
    const float* pb = points + (size_t)b * 9 * ZYX;

    int V = cnt[b];
    if (V > CAP) V = CAP;
    for (int i = tid; i < V; i += 256) {
        s_rawsc[i] = csc[b * CAP + i];
        s_rawidx[i] = cidx[b * CAP + i];
    }
    if (tid < NSLOT_MAX) { s_supx[tid] = 0ull; s_supy[tid] = 0ull; }
    __syncthreads();

    int M = V < MMAX ? V : MMAX;

    // exact ranking: descending score, ties -> ascending index (lax.top_k order)
    for (int i = tid; i < V; i += 256) {
        float si = s_rawsc[i];
        int ii = s_rawidx[i];
        int rank = 0;
        for (int j = 0; j < V; ++j) {
            float sj = s_rawsc[j];
            int ij = s_rawidx[j];
            rank += (sj > si) || (sj == si && ij < ii);
        }
        if (rank < MMAX) {
            s_sc[rank] = si;
            s_idx[rank] = ii;
        }
    }
    __syncthreads(); // raw arrays dead beyond this point

    // decode sorted candidates into AoS box arrays (aliases raw region)
    for (int m = tid; m < M; m += 256) {
        float cx, cy, cz, w, h, l, th;
        decode_one(pb, s_idx[m], cx, cy, cz, w, h, l, th);
        float xmn, ymn, xmx, ymx, zmn, zmx;
        corner_boxes(cx, cy, cz, w, h, l, th, xmn, ymn, xmx, ymx, zmn, zmx);
        s_bxy[m] = make_float4(xmn, ymn, xmx, ymx);
        s_byz[m] = make_float4(ymn, zmn, ymx, zmx);
        float axy = fmaxf(xmx - xmn, 0.0f) * fmaxf(ymx - ymn, 0.0f);
        float ayz = fmaxf(ymx - ymn, 0.0f) * fmaxf(zmx - zmn, 0.0f);
        s_ar[m] = make_float2(axy, ayz);
    }
    __syncthreads();

    // wave-0 greedy NMS with ballot-built wave-uniform suppression words
    if (tid < 64) {
        int lane = tid;
        // preload candidates 0..255 into registers (covers expected V~244)
        float4 rxy[RSLOTS], ryz[RSLOTS];
        float2 rar[RSLOTS];
#pragma unroll
        for (int s = 0; s < RSLOTS; ++s) {
            int j = (s << 6) | lane;
            rxy[s] = s_bxy[j];
            ryz[s] = s_byz[j];
            rar[s] = s_ar[j];
        }
        int kept_cap = n_out < KEPT_MAX ? n_out : KEPT_MAX;
        int nslot = (M + 63) >> 6;
        unsigned long long cur_sx = 0ull, cur_sy = 0ull;
        int curslot = 0;
        int n_kept = 0;
        for (int i = 0; i < M; ++i) {
            int sl = i >> 6;
            if (sl != curslot) { // advance to next suppression word
                curslot = sl;
                cur_sx = s_supx[sl];
                cur_sy = s_supy[sl];
            }
            bool kx = !((cur_sx >> (i & 63)) & 1ull);
            bool ky = !((cur_sy >> (i & 63)) & 1ull);
            if (!(kx | ky)) continue; // register-only, ~5 cy
            if (lane == 0) s_kept[n_kept] = i;
            n_kept++;
            if (n_kept >= kept_cap) break;
            float4 ixy = s_bxy[i];
            float4 iyz = s_byz[i];
            float2 iar = s_ar[i];
#pragma unroll
            for (int s = 0; s < NSLOT_MAX; ++s) {
                if (s < curslot || s >= nslot) continue;
                int j = (s << 6) | lane;
                float4 jxy, jyz;
                float2 jar;
                if (s < RSLOTS) { jxy = rxy[s]; jyz = ryz[s]; jar = rar[s]; }
                else            { jxy = s_bxy[j]; jyz = s_byz[j]; jar = s_ar[j]; }
                bool vld = (j > i) && (j < M);
                if (kx) {
                    float lt0 = fmaxf(ixy.x, jxy.x), lt1 = fmaxf(ixy.y, jxy.y);
                    float rb0 = fminf(ixy.z, jxy.z), rb1 = fminf(ixy.w, jxy.w);
                    float inter = fmaxf(rb0 - lt0, 0.0f) * fmaxf(rb1 - lt1, 0.0f);
                    float uni = iar.x + jar.x - inter;
                    bool sup = vld && (inter / fmaxf(uni, 1e-9f) > IOU_THR);
                    unsigned long long mk = __ballot(sup);
                    if (mk) {
                        if (s == curslot) cur_sx |= mk;
                        else if (lane == 0) s_supx[s] |= mk;
                    }
                }
                if (ky) {
                    float lt0 = fmaxf(iyz.x, jyz.x), lt1 = fmaxf(iyz.y, jyz.y);
                    float rb0 = fminf(iyz.z, jyz.z), rb1 = fminf(iyz.w, jyz.w);
                    float inter = fmaxf(rb0 - lt0, 0.0f) * fmaxf(rb1 - lt1, 0.0f);
                    float uni = iar.y + jar.y - inter;
                    bool sup = vld && (inter / fmaxf(uni, 1e-9f) > IOU_THR);
                    unsigned long long mk = __ballot(sup);
                    if (mk) {
                        if (s == curslot) cur_sy |= mk;
                        else if (lane == 0) s_supy[s] |= mk;
                    }
                }
            }
        }
        if (lane == 0) s_nkept = n_kept < kept_cap ? n_kept : kept_cap;
    }
    __syncthreads();

    // emit: boxes (B, n_out, 9) then scores (B, n_out); zero-pad beyond n_kept
    int nk = s_nkept;
    float* boxes_out = out;
    float* scores_out = out + (size_t)B * n_out * 9;
    for (int p = tid; p < n_out; p += 256) {
        float o[9] = {0, 0, 0, 0, 0, 0, 0, 0, 0};
        float sc = 0.0f;
        if (p < nk) {
            int m = s_kept[p];
            float cx, cy, cz, w, h, l, th;
            decode_one(pb, s_idx[m], cx, cy, cz, w, h, l, th);
            o[0] = cx; o[1] = cy; o[2] = cz;
            o[3] = w;  o[4] = h;  o[5] = l;
            o[6] = 0.0f; o[7] = th; o[8] = 0.0f;
            sc = s_sc[m];
        }
        float* bo = boxes_out + ((size_t)b * n_out + p) * 9;
#pragma unroll
        for (int k = 0; k < 9; ++k) bo[k] = o[k];
        scores_out[(size_t)b * n_out + p] = sc;
    }
}

extern "C" void kernel_launch(void* const* d_in, const int* in_sizes, int n_in,
                              void* d_out, int out_size, void* d_ws, size_t ws_size,
                              hipStream_t stream) {
    const float* points = (const float*)d_in[0];
    int B = in_sizes[0] / (9 * ZYX);  // 4
    int n_out = out_size / (B * 10);  // 50

    char* ws = (char*)d_ws;
    int* cnt = (int*)ws;
    float* csc = (float*)(ws + 256);
    int* cidx = (int*)(ws + 256 + (size_t)B * CAP * sizeof(float));

    hipMemsetAsync(cnt, 0, 256, stream);

    int total4 = B * (ZYX / 4);
    collect_kernel<<<(total4 + 255) / 256, 256, 0, stream>>>(points, B, cnt, csc, cidx);
    nms_kernel<<<B, 256, 0, stream>>>(points, cnt, csc, cidx, (float*)d_out, B, n_out);
}

// Round 3
// 296.090 us; speedup vs baseline: 1.0535x; 1.0535x over previous
//
#include <hip/hip_runtime.h>

#define ZYX (64 * 128 * 128) /* 1048576 */
#define CAP 2048
#define MMAX 1024
#define MADJ 320           /* fast-path max candidates for LDS adjacency */
#define NS 5               /* MADJ/64 suppression words per row */
#define KEPT_MAX 512
#define CLS_THR 0.5f
#define IOU_THR 0.5f

// ---------------- decode helper (matches reference _decode exactly) ----------
__device__ __forceinline__ void decode_one(const float* __restrict__ pb, int f,
                                           float& cx, float& cy, float& cz,
                                           float& w, float& h, float& l, float& th) {
    const float TM[8] = {-0.25f, 0.01f, 0.26f, 0.46f, 0.26f, 0.62f, 0.69f, 1.46f};
    const float TS[8] = {0.93f, 0.26f, 0.53f, 0.89f, 1.11f, 0.13f, 0.16f, 0.19f};
    int z = f >> 14;
    int y = (f >> 7) & 127;
    int x = f & 127;
    float r[8];
#pragma unroll
    for (int c = 0; c < 8; ++c)
        r[c] = pb[(size_t)(c + 1) * ZYX + f] * TS[c] + TM[c];
    th = atan2f(r[1], r[0]);
    cx = (-16.0f + 0.25f * (float)x) + r[2];
    cy = (-16.0f + 0.25f * (float)y) + r[3];
    cz = (-16.0f + 0.5f * (float)z) + r[4];
    w = expf(r[5]);
    h = expf(r[6]);
    l = expf(r[7]);
}

__device__ __forceinline__ void corner_boxes(float cx, float cy, float cz,
                                             float w, float h, float l, float th,
                                             float& xmn, float& ymn, float& xmx, float& ymx,
                                             float& zmn, float& zmx) {
    float ct = cosf(th), st = sinf(th);
    xmn = 1e30f; xmx = -1e30f; ymn = 1e30f; ymx = -1e30f; zmn = 1e30f; zmx = -1e30f;
#pragma unroll
    for (int k = 0; k < 8; ++k) {
        float sx = (k & 4) ? -1.0f : 1.0f;
        float sy = (k & 2) ? -1.0f : 1.0f;
        float sz = (k & 1) ? -1.0f : 1.0f;
        float ox = 0.5f * sx * w;
        float oy = 0.5f * sy * h;
        float oz = 0.5f * sz * l;
        float px = cx + ct * ox + st * oz;
        float py = cy + oy;
        float pz = cz - st * ox + ct * oz;
        xmn = fminf(xmn, px); xmx = fmaxf(xmx, px);
        ymn = fminf(ymn, py); ymx = fmaxf(ymx, py);
        zmn = fminf(zmn, pz); zmx = fmaxf(zmx, pz);
    }
}

// IoU > thr test, mirroring reference float op order
__device__ __forceinline__ bool iou_over(const float4& a, float aarea,
                                         const float4& b, float barea) {
    float lt0 = fmaxf(a.x, b.x), lt1 = fmaxf(a.y, b.y);
    float rb0 = fminf(a.z, b.z), rb1 = fminf(a.w, b.w);
    float inter = fmaxf(rb0 - lt0, 0.0f) * fmaxf(rb1 - lt1, 0.0f);
    float uni = aarea + barea - inter;
    return inter / fmaxf(uni, 1e-9f) > IOU_THR;
}

// ---------------- kernel 1: compact candidates with score > CLS_THR ----------
__global__ __launch_bounds__(256) void collect_kernel(const float* __restrict__ points, int B,
                                                      int* __restrict__ cnt,
                                                      float* __restrict__ csc,
                                                      int* __restrict__ cidx) {
    int g = blockIdx.x * blockDim.x + threadIdx.x;
    int per_b4 = ZYX / 4;
    int total4 = B * per_b4;
    if (g >= total4) return;
    int b = g / per_b4;
    int f4 = g - b * per_b4;
    const float4* p = (const float4*)(points + (size_t)b * 9 * ZYX);
    float4 v = p[f4];
    float vals[4] = {v.x, v.y, v.z, v.w};
    int f = f4 * 4;
#pragma unroll
    for (int k = 0; k < 4; ++k) {
        if (vals[k] > CLS_THR) {
            int pos = atomicAdd(&cnt[b], 1);
            if (pos < CAP) {
                csc[b * CAP + pos] = vals[k];
                cidx[b * CAP + pos] = f + k;
            }
        }
    }
}

// ---------------- kernel 2: rank + decode -> workspace ----------------------
// ws rows (per batch, MMAX rows): box9 = 8 floats (cx,cy,cz,w,h,l,th,sc)
//                                 bxy = float4, byz = float4, ar = float2
__global__ __launch_bounds__(256) void prep_kernel(const float* __restrict__ points,
                                                   const int* __restrict__ cnt,
                                                   const float* __restrict__ csc,
                                                   const int* __restrict__ cidx,
                                                   float* __restrict__ wbox9,
                                                   float4* __restrict__ wbxy,
                                                   float4* __restrict__ wbyz,
                                                   float2* __restrict__ war) {
    __shared__ float s_sc[CAP];
    __shared__ int s_ix[CAP];
    int b = blockIdx.x;
    int tid = threadIdx.x;
    const float* pb = points + (size_t)b * 9 * ZYX;

    int V = cnt[b];
    if (V > CAP) V = CAP;
    for (int i = tid; i < V; i += 256) {
        s_sc[i] = csc[b * CAP + i];
        s_ix[i] = cidx[b * CAP + i];
    }
    __syncthreads();

    // each thread ranks + decodes its own candidate, writes to its rank's row
    for (int i = tid; i < V; i += 256) {
        float si = s_sc[i];
        int ii = s_ix[i];
        int r = 0;
        for (int j = 0; j < V; ++j) {
            float sj = s_sc[j];
            int ij = s_ix[j];
            r += (sj > si) || (sj == si && ij < ii);
        }
        if (r < MMAX) {
            float cx, cy, cz, w, h, l, th;
            decode_one(pb, ii, cx, cy, cz, w, h, l, th);
            float xmn, ymn, xmx, ymx, zmn, zmx;
            corner_boxes(cx, cy, cz, w, h, l, th, xmn, ymn, xmx, ymx, zmn, zmx);
            int row = b * MMAX + r;
            float4* b9 = (float4*)(wbox9 + (size_t)row * 8);
            b9[0] = make_float4(cx, cy, cz, w);
            b9[1] = make_float4(h, l, th, si);
            wbxy[row] = make_float4(xmn, ymn, xmx, ymx);
            wbyz[row] = make_float4(ymn, zmn, ymx, zmx);
            float axy = fmaxf(xmx - xmn, 0.0f) * fmaxf(ymx - ymn, 0.0f);
            float ayz = fmaxf(ymx - ymn, 0.0f) * fmaxf(zmx - zmn, 0.0f);
            war[row] = make_float2(axy, ayz);
        }
    }
}

// ---------------- kernel 3: adjacency NMS + emit ----------------------------
__global__ __launch_bounds__(256) void finish_kernel(const int* __restrict__ cnt,
                                                     const float* __restrict__ wbox9,
                                                     const float4* __restrict__ wbxy,
                                                     const float4* __restrict__ wbyz,
                                                     const float2* __restrict__ war,
                                                     float* __restrict__ out,
                                                     int B, int n_out) {
    __shared__ float4 s_bxy[MADJ], s_byz[MADJ];
    __shared__ float2 s_ar[MADJ];
    __shared__ float s_b9[MADJ * 8];
    __shared__ unsigned long long s_ax[MADJ * NS], s_ay[MADJ * NS];
    __shared__ int s_kept[KEPT_MAX];
    __shared__ int s_nkept;

    int b = blockIdx.x;
    int tid = threadIdx.x;
    int V = cnt[b];
    if (V > CAP) V = CAP;
    int M = V < MMAX ? V : MMAX;
    int cap = n_out < KEPT_MAX ? n_out : KEPT_MAX;
    bool fast = (M <= MADJ);

    if (fast) {
        // stage boxes into LDS
        for (int m = tid; m < M; m += 256) {
            int row = b * MMAX + m;
            s_bxy[m] = wbxy[row];
            s_byz[m] = wbyz[row];
            s_ar[m] = war[row];
            const float4* b9 = (const float4*)(wbox9 + (size_t)row * 8);
            ((float4*)s_b9)[m * 2] = b9[0];
            ((float4*)s_b9)[m * 2 + 1] = b9[1];
        }
        for (int k = tid; k < M * NS; k += 256) { s_ax[k] = 0ull; s_ay[k] = 0ull; }
        __syncthreads();

        // parallel adjacency build: mirrored-row partition for balance
        int half = (M + 1) >> 1;
        for (int r0 = tid; r0 < half; r0 += 256) {
#pragma unroll
            for (int side = 0; side < 2; ++side) {
                int i = side ? (M - 1 - r0) : r0;
                if (side && i == r0) continue;
                float4 ixy = s_bxy[i], iyz = s_byz[i];
                float2 ia = s_ar[i];
                for (int j = i + 1; j < M; ++j) {
                    float4 jxy = s_bxy[j];
                    float2 ja = s_ar[j];
                    if (iou_over(ixy, ia.x, jxy, ja.x))
                        atomicOr(&s_ax[i * NS + (j >> 6)], 1ull << (j & 63));
                    float4 jyz = s_byz[j];
                    if (iou_over(iyz, ia.y, jyz, ja.y))
                        atomicOr(&s_ay[i * NS + (j >> 6)], 1ull << (j & 63));
                }
            }
        }
        __syncthreads();

        // serial greedy scan: pure bit ops, thread 0
        if (tid == 0) {
            unsigned long long sx[NS], sy[NS];
#pragma unroll
            for (int t = 0; t < NS; ++t) { sx[t] = 0ull; sy[t] = 0ull; }
            int nk = 0;
            bool done = false;
#pragma unroll
            for (int s = 0; s < NS; ++s) {
                if (!done) {
                    for (int bit = 0; bit < 64; ++bit) {
                        int i = s * 64 + bit;
                        if (i >= M) break;
                        bool kx = !((sx[s] >> bit) & 1ull);
                        bool ky = !((sy[s] >> bit) & 1ull);
                        if (!(kx | ky)) continue;
                        s_kept[nk++] = i;
                        if (nk >= cap) { done = true; break; }
                        if (kx) {
#pragma unroll
                            for (int t = 0; t < NS; ++t) sx[t] |= s_ax[i * NS + t];
                        }
                        if (ky) {
#pragma unroll
                            for (int t = 0; t < NS; ++t) sy[t] |= s_ay[i * NS + t];
                        }
                    }
                }
            }
            s_nkept = nk;
        }
    } else {
        // cold fallback (M > MADJ): single-thread O(M^2) greedy, sup flags in LDS
        if (tid == 0) {
            char* supx = (char*)s_ax;
            char* supy = (char*)s_ay;
            for (int i = 0; i < M; ++i) { supx[i] = 0; supy[i] = 0; }
            int nk = 0;
            for (int i = 0; i < M && nk < cap; ++i) {
                bool kx = !supx[i], ky = !supy[i];
                if (!(kx | ky)) continue;
                s_kept[nk++] = i;
                if (nk >= cap) break;
                int row = b * MMAX + i;
                float4 ixy = wbxy[row], iyz = wbyz[row];
                float2 ia = war[row];
                for (int j = i + 1; j < M; ++j) {
                    int jr = b * MMAX + j;
                    if (kx && !supx[j]) {
                        if (iou_over(ixy, ia.x, wbxy[jr], war[jr].x)) supx[j] = 1;
                    }
                    if (ky && !supy[j]) {
                        if (iou_over(iyz, ia.y, wbyz[jr], war[jr].y)) supy[j] = 1;
                    }
                }
            }
            s_nkept = nk;
        }
    }
    __syncthreads();

    // emit: boxes (B, n_out, 9) then scores (B, n_out); zero-pad beyond n_kept
    int nk = s_nkept;
    float* boxes_out = out;
    float* scores_out = out + (size_t)B * n_out * 9;
    for (int p = tid; p < n_out; p += 256) {
        float o[9] = {0, 0, 0, 0, 0, 0, 0, 0, 0};
        float sc = 0.0f;
        if (p < nk) {
            int m = s_kept[p];
            float v[8];
            if (fast) {
#pragma unroll
                for (int k = 0; k < 8; ++k) v[k] = s_b9[m * 8 + k];
            } else {
#pragma unroll
                for (int k = 0; k < 8; ++k) v[k] = wbox9[(size_t)(b * MMAX + m) * 8 + k];
            }
            o[0] = v[0]; o[1] = v[1]; o[2] = v[2]; // cx cy cz
            o[3] = v[3]; o[4] = v[4]; o[5] = v[5]; // w h l
            o[6] = 0.0f; o[7] = v[6]; o[8] = 0.0f; // theta in slot 7
            sc = v[7];
        }
        float* bo = boxes_out + ((size_t)b * n_out + p) * 9;
#pragma unroll
        for (int k = 0; k < 9; ++k) bo[k] = o[k];
        scores_out[(size_t)b * n_out + p] = sc;
    }
}

extern "C" void kernel_launch(void* const* d_in, const int* in_sizes, int n_in,
                              void* d_out, int out_size, void* d_ws, size_t ws_size,
                              hipStream_t stream) {
    const float* points = (const float*)d_in[0];
    int B = in_sizes[0] / (9 * ZYX);  // 4
    int n_out = out_size / (B * 10);  // 50

    // workspace layout
    char* ws = (char*)d_ws;
    size_t off = 0;
    int* cnt = (int*)(ws + off); off += 256;
    float* csc = (float*)(ws + off); off += (size_t)B * CAP * 4;
    int* cidx = (int*)(ws + off); off += (size_t)B * CAP * 4;
    float* wbox9 = (float*)(ws + off); off += (size_t)B * MMAX * 8 * 4;
    float4* wbxy = (float4*)(ws + off); off += (size_t)B * MMAX * 16;
    float4* wbyz = (float4*)(ws + off); off += (size_t)B * MMAX * 16;
    float2* war = (float2*)(ws + off); off += (size_t)B * MMAX * 8;

    hipMemsetAsync(cnt, 0, 256, stream);

    int total4 = B * (ZYX / 4);
    collect_kernel<<<(total4 + 255) / 256, 256, 0, stream>>>(points, B, cnt, csc, cidx);
    prep_kernel<<<B, 256, 0, stream>>>(points, cnt, csc, cidx, wbox9, wbxy, wbyz, war);
    finish_kernel<<<B, 256, 0, stream>>>(cnt, wbox9, wbxy, wbyz, war, (float*)d_out, B, n_out);
}